// Round 3
// baseline (218.253 us; speedup 1.0000x reference)
//
#include <hip/hip_runtime.h>
#include <hip/hip_bf16.h>

#define BB 16
#define NN 4096
#define DD 64
#define NM1 4095

typedef __bf16 bf16x8 __attribute__((ext_vector_type(8)));
typedef float f32x4 __attribute__((ext_vector_type(4)));

typedef __attribute__((address_space(1))) const void gas_void;
typedef __attribute__((address_space(3))) void las_void;

// ws layout:
//   [0]                  float mx[4096]          (16 KB)  -- zeroed via memsetAsync
//   [16384]              float ss[4096]          (16 KB)  -- zeroed via memsetAsync
//   [32768]              __bf16 XT[16][64][4096] ( 8 MiB)
//   [32768 + 8 MiB]      __bf16 A16[4096][4096]  (32 MiB)

// ---------------------------------------------------------------------------
// Kernel 1: flat scatter build. j-major: lane-consecutive loads AND stores.
// ---------------------------------------------------------------------------
__global__ __launch_bounds__(256) void build_kernel(
    const float* __restrict__ inc, float* __restrict__ out_inc,
    __bf16* __restrict__ A16, float* __restrict__ mxa, float* __restrict__ ssa)
{
    int t = threadIdx.x;
    int base = blockIdx.x << 12;                 // 4096 elems per block
    int rA = (int)((unsigned)base / NM1);        // block spans rows {rA, rA+1}
    float pm0 = 0.f, ps0 = 0.f, pm1 = 0.f, ps1 = 0.f;
    #pragma unroll
    for (int j = 0; j < 16; ++j) {
        int f = base + j * 256 + t;              // < 2^24, exact coverage
        int i = (int)((unsigned)f / NM1);
        int c = f - i * NM1;
        float x = inc[f];
        float w = x > 0.01f ? x : 0.f;
        int dst = f + i + (c >= i);              // i*4096 + c + (c>=i)
        out_inc[dst] = w;
        A16[dst] = (__bf16)w;
        if (i == rA) { pm0 = fmaxf(pm0, w); ps0 += w * w; }
        else         { pm1 = fmaxf(pm1, w); ps1 += w * w; }
    }
    #pragma unroll
    for (int off = 32; off; off >>= 1) {
        pm0 = fmaxf(pm0, __shfl_down(pm0, off));
        ps0 += __shfl_down(ps0, off);
        pm1 = fmaxf(pm1, __shfl_down(pm1, off));
        ps1 += __shfl_down(ps1, off);
    }
    __shared__ float sm0[4], sq0[4], sm1[4], sq1[4];
    int wid = t >> 6;
    if ((t & 63) == 0) { sm0[wid] = pm0; sq0[wid] = ps0; sm1[wid] = pm1; sq1[wid] = ps1; }
    __syncthreads();
    if (t == 0) {
        float m0v = fmaxf(fmaxf(sm0[0], sm0[1]), fmaxf(sm0[2], sm0[3]));
        float s0v = sq0[0] + sq0[1] + sq0[2] + sq0[3];
        float m1v = fmaxf(fmaxf(sm1[0], sm1[1]), fmaxf(sm1[2], sm1[3]));
        float s1v = sq1[0] + sq1[1] + sq1[2] + sq1[3];
        atomicMax((unsigned*)(mxa + rA), __float_as_uint(m0v));  // w >= 0
        atomicAdd(ssa + rA, s0v);
        int rB = rA + 1;
        if (rB < NN) {
            atomicMax((unsigned*)(mxa + rB), __float_as_uint(m1v));
            atomicAdd(ssa + rB, s1v);
        }
    }
}

// ---------------------------------------------------------------------------
// Kernel 2: XT[b][d][n] = (bf16)X[b][n][d]  (64x64 tiles via LDS) + diagonal
// ---------------------------------------------------------------------------
__global__ __launch_bounds__(256) void xt_kernel(
    const float* __restrict__ X, __bf16* __restrict__ XT,
    float* __restrict__ out_inc, __bf16* __restrict__ A16)
{
    __shared__ __bf16 tile[64 * 72];             // stride 72 elems = 144 B
    int t = threadIdx.x;
    int ntile = blockIdx.x, b = blockIdx.y;
    int n = t >> 2, q = t & 3;
    const float* src = X + ((size_t)b * NN + ntile * 64 + n) * DD + q * 16;
    #pragma unroll
    for (int v = 0; v < 4; ++v) {
        f32x4 u = *(const f32x4*)(src + v * 4);
        #pragma unroll
        for (int j = 0; j < 4; ++j) {
            int d = q * 16 + v * 4 + j;
            tile[d * 72 + n] = (__bf16)u[j];
        }
    }
    __syncthreads();
    int d = t >> 2;
    __bf16* dst = XT + ((size_t)b * DD + d) * NN + ntile * 64 + q * 16;
    *(bf16x8*)dst       = *(bf16x8*)&tile[d * 72 + q * 16];
    *(bf16x8*)(dst + 8) = *(bf16x8*)&tile[d * 72 + q * 16 + 8];
    if (b == 0 && t < 64) {                      // diagonal of W + I
        int r = ntile * 64 + t;
        out_inc[(size_t)r * NN + r] = 1.0f;
        A16[(size_t)r * NN + r] = (__bf16)1.0f;
    }
}

// ---------------------------------------------------------------------------
// Kernel 3: acc = A16 @ X[b] via MFMA. Hybrid operand sourcing:
//   A: direct global->register loads (read-once stream; MFMA-shaped access,
//      4 lanes/row = 64 B contiguous). Depth-2 reg pipeline, 4 static sets.
//   B (XT): LDS-staged via global_load_lds (4x dedup across waves), 4 x 16 KB
//      quad-buffer, XOR-octet swizzle.
//   LDS port traffic/k-step: 16 KB write + 64 KB read (vs 128 KB in R1).
//   1 counted vmcnt(12) + 1 raw s_barrier per k-step; never drains in loop.
//   512 thr / 8 waves (2/SIMD); wave = 32 rows x 64 cols x 1 batch.
// ---------------------------------------------------------------------------
__global__ __launch_bounds__(512, 2) void gemm_loss_kernel(
    const __bf16* __restrict__ A16, const __bf16* __restrict__ XT,
    const float* __restrict__ X, const float* __restrict__ rproj,
    const float* __restrict__ mxa, const float* __restrict__ ssa,
    float* __restrict__ loss)
{
    __shared__ __bf16 smem[4 * 8192];            // 4 B-buffers x 16 KB = 64 KB

    const int t = threadIdx.x;
    const int wave = t >> 6, lane = t & 63;
    const int quad = lane >> 4, ln = lane & 15;
    const int sr = lane >> 3, so = lane & 7;     // staging row-in-group / octet
    const int bq = wave >> 2;                    // batch within pair (0/1)
    const int wr = (wave & 3) << 5;              // wave row offset: 0/32/64/96
    const int m0 = blockIdx.x * 128;
    const int b0 = blockIdx.y * 2;

    const __bf16* XTb = XT + (size_t)b0 * DD * NN;   // 2 batches, flat 128 rows

    // B staging sources (advance 128 B per k-step). r&7 == sr for both p.
    const int rp0 = (wave << 3) + sr;            // rows 0..63   (p=0)
    const int og  = so ^ sr;
    const __bf16* srcB0 = XTb + (size_t)rp0 * NN + og * 8;
    const __bf16* srcB1 = XTb + (size_t)(rp0 + 64) * NN + og * 8;

    // A fragment sources (advance 128 B per k-step), MFMA-native layout:
    // lane quad*16+ln -> A[m0+wr+mt*16+ln][quad*8 .. +8] (+64B for k+32)
    const __bf16* aA0 = A16 + (size_t)(m0 + wr + ln) * NN + quad * 8;
    const __bf16* aA1 = aA0 + (size_t)16 * NN;

    f32x4 acc[2][4];
    f32x4 zero = {0.f, 0.f, 0.f, 0.f};
    #pragma unroll
    for (int mt = 0; mt < 2; ++mt)
        #pragma unroll
        for (int ct = 0; ct < 4; ++ct) acc[mt][ct] = zero;

    bf16x8 afr[4][2][2];                         // set x mt x k-half

#define STAGE(BUF) do {                                                        \
    __builtin_amdgcn_global_load_lds((gas_void*)srcB0,                         \
        (las_void*)(smem + (BUF) * 8192 + (wave << 3) * 64), 16, 0, 0);        \
    __builtin_amdgcn_global_load_lds((gas_void*)srcB1,                         \
        (las_void*)(smem + (BUF) * 8192 + (64 + (wave << 3)) * 64), 16, 0, 0); \
    srcB0 += 64; srcB1 += 64; } while (0)

#define LOADA(S) do {                                                          \
    asm volatile("global_load_dwordx4 %0, %2, off\n\t"                         \
                 "global_load_dwordx4 %1, %2, off offset:64"                   \
                 : "=&v"(afr[S][0][0]), "=&v"(afr[S][0][1]) : "v"(aA0));       \
    asm volatile("global_load_dwordx4 %0, %2, off\n\t"                         \
                 "global_load_dwordx4 %1, %2, off offset:64"                   \
                 : "=&v"(afr[S][1][0]), "=&v"(afr[S][1][1]) : "v"(aA1));       \
    aA0 += 64; aA1 += 64; } while (0)

#define VMCNT(N) asm volatile("s_waitcnt vmcnt(" #N ")" ::: "memory")

#define COMPUTE(S) do {                                                        \
    const __bf16* bX_ = smem + (S) * 8192 + (bq << 12);                        \
    _Pragma("unroll")                                                          \
    for (int h = 0; h < 2; ++h) {                                              \
        const int oc = (h << 2) + quad;                                        \
        bf16x8 bfr[4];                                                         \
        _Pragma("unroll")                                                      \
        for (int ct = 0; ct < 4; ++ct) {                                       \
            const int n = ct * 16 + ln;                                        \
            bfr[ct] = *(const bf16x8*)&bX_[n * 64 + ((oc ^ (n & 7)) << 3)];    \
        }                                                                      \
        _Pragma("unroll")                                                      \
        for (int ct = 0; ct < 4; ++ct) {                                       \
            acc[0][ct] = __builtin_amdgcn_mfma_f32_16x16x32_bf16(              \
                afr[S][0][h], bfr[ct], acc[0][ct], 0, 0, 0);                   \
            acc[1][ct] = __builtin_amdgcn_mfma_f32_16x16x32_bf16(              \
                afr[S][1][h], bfr[ct], acc[1][ct], 0, 0, 0);                   \
        }                                                                      \
    } } while (0)

#define STEP(S, T2, STG, VMN) do {                                             \
    if (STG) { STAGE(T2); LOADA(T2); }                                         \
    VMCNT(VMN);                                                                \
    __builtin_amdgcn_sched_barrier(0);                                         \
    __builtin_amdgcn_s_barrier();                                              \
    __builtin_amdgcn_sched_barrier(0);                                         \
    COMPUTE(S); } while (0)

    // prologue: issue k-steps 0 and 1 (B->LDS, A->regs)
    STAGE(0); LOADA(0);
    STAGE(1); LOADA(1);

    // steady state: 15 groups x 4 k-steps (kt = 4g+j, buffers = j)
    for (int g = 0; g < 15; ++g) {
        STEP(0, 2, true, 12);
        STEP(1, 3, true, 12);
        STEP(2, 0, true, 12);
        STEP(3, 1, true, 12);
    }
    // tail group: kt = 60..63
    STEP(0, 2, true, 12);
    STEP(1, 3, true, 12);
    STEP(2, 0, false, 6);
    STEP(3, 0, false, 0);

#undef STEP
#undef COMPUTE
#undef VMCNT
#undef LOADA
#undef STAGE

    __syncthreads();                             // drain before buffer reuse

    // ---- phase 2 staging: XA[2][128][64] = bf16(X rows), R[64][64] = r+I ----
    {
        const int rr = t >> 2, q = t & 3;        // rr in [0,128)
        #pragma unroll
        for (int bb = 0; bb < 2; ++bb) {
            const float* xs = X + ((size_t)(b0 + bb) * NN + m0 + rr) * DD + q * 16;
            __bf16* XA = smem + bb * 8192;
            #pragma unroll
            for (int v = 0; v < 2; ++v) {
                f32x4 u0 = *(const f32x4*)(xs + v * 8);
                f32x4 u1 = *(const f32x4*)(xs + v * 8 + 4);
                bf16x8 w;
                #pragma unroll
                for (int j = 0; j < 4; ++j) { w[j] = (__bf16)u0[j]; w[j + 4] = (__bf16)u1[j]; }
                const int o = (q * 2 + v) ^ (rr & 7);
                *(bf16x8*)&XA[rr * 64 + o * 8] = w;
            }
        }
        if (t < 256) {
            const int rr2 = t >> 2, q2 = t & 3;  // rr2 in [0,64): rproj row e
            const float* rs = rproj + (size_t)rr2 * DD + q2 * 16;
            __bf16* R = smem + 16384;
            #pragma unroll
            for (int v = 0; v < 4; ++v) {
                f32x4 u = *(const f32x4*)(rs + v * 4);
                #pragma unroll
                for (int j = 0; j < 4; ++j) {
                    const int d = q2 * 16 + v * 4 + j;
                    float val = u[j] + (d == rr2 ? 1.0f : 0.0f);   // r + I
                    R[d * 64 + (((rr2 >> 3) ^ (d & 7)) << 3) + (rr2 & 7)] = (__bf16)val;
                }
            }
        }
    }
    __syncthreads();

    // ---- xp phase accumulates into -acc: dif = X@(r+I) - acc ----
    #pragma unroll
    for (int mt = 0; mt < 2; ++mt)
        #pragma unroll
        for (int ct = 0; ct < 4; ++ct) acc[mt][ct] = -acc[mt][ct];

    {
        const __bf16* XA = smem + bq * 8192;
        const __bf16* R  = smem + 16384;
        #pragma unroll
        for (int kk = 0; kk < DD; kk += 32) {
            const int oc = (kk >> 3) + quad;
            bf16x8 af[2], bfr[4];
            #pragma unroll
            for (int mt = 0; mt < 2; ++mt) {
                const int r = wr + mt * 16 + ln;
                af[mt] = *(const bf16x8*)&XA[r * 64 + ((oc ^ (r & 7)) << 3)];
            }
            #pragma unroll
            for (int ct = 0; ct < 4; ++ct) {
                const int n = ct * 16 + ln;
                bfr[ct] = *(const bf16x8*)&R[n * 64 + ((oc ^ (n & 7)) << 3)];
            }
            #pragma unroll
            for (int mt = 0; mt < 2; ++mt)
                #pragma unroll
                for (int ct = 0; ct < 4; ++ct)
                    acc[mt][ct] = __builtin_amdgcn_mfma_f32_16x16x32_bf16(
                        af[mt], bfr[ct], acc[mt][ct], 0, 0, 0);
        }
    }

    // ---- epilogue: C/D layout col=ln, row=quad*4+reg; wave owns full rows ----
    #pragma unroll
    for (int mt = 0; mt < 2; ++mt) {
        #pragma unroll
        for (int rg = 0; rg < 4; ++rg) {
            float s = 0.f;
            #pragma unroll
            for (int ct = 0; ct < 4; ++ct) {
                float d = acc[mt][ct][rg];
                s += d * d;
            }
            s += __shfl_xor(s, 1);
            s += __shfl_xor(s, 2);
            s += __shfl_xor(s, 4);
            s += __shfl_xor(s, 8);
            if (ln == 0) {
                int row = m0 + wr + mt * 16 + quad * 4 + rg;
                loss[(size_t)(b0 + bq) * NN + row] =
                    0.2f * sqrtf(s) + mxa[row] + 0.001f * sqrtf(ssa[row]);
            }
        }
    }
}

extern "C" void kernel_launch(void* const* d_in, const int* in_sizes, int n_in,
                              void* d_out, int out_size, void* d_ws, size_t ws_size,
                              hipStream_t stream) {
    const float* X   = (const float*)d_in[0];   // [B][N][D] f32
    const float* r   = (const float*)d_in[1];   // [D][D] f32
    const float* inc = (const float*)d_in[2];   // [N][N-1] f32
    float* out      = (float*)d_out;
    float* out_loss = out;                       // [B][N]
    float* out_inc  = out + (size_t)BB * NN;     // [N][N]

    char* ws = (char*)d_ws;
    float*  mxa = (float*)ws;                               // 16 KB
    float*  ssa = (float*)(ws + 16384);                     // 16 KB
    __bf16* XT  = (__bf16*)(ws + 32768);                    //  8 MiB
    __bf16* A16 = (__bf16*)(ws + 32768 + (size_t)8 * 1024 * 1024);  // 32 MiB

    hipMemsetAsync(mxa, 0, 32768, stream);      // zero mx/ss accumulators

    hipLaunchKernelGGL(build_kernel, dim3(NM1), dim3(256), 0, stream,
                       inc, out_inc, A16, mxa, ssa);
    hipLaunchKernelGGL(xt_kernel, dim3(NN / 64, BB), dim3(256), 0, stream,
                       X, XT, out_inc, A16);
    hipLaunchKernelGGL(gemm_loss_kernel, dim3(NN / 128, BB / 2), dim3(512), 0, stream,
                       A16, XT, X, r, mxa, ssa, out_loss);
}

// Round 4
// 185.871 us; speedup vs baseline: 1.1742x; 1.1742x over previous
//
#include <hip/hip_runtime.h>
#include <hip/hip_bf16.h>

#define BB 16
#define NN 4096
#define DD 64
#define NM1 4095

typedef __bf16 bf16x8 __attribute__((ext_vector_type(8)));
typedef float f32x4 __attribute__((ext_vector_type(4)));

typedef __attribute__((address_space(1))) const void gas_void;
typedef __attribute__((address_space(3))) void las_void;

// ws layout:
//   [0]                  float mx[4096]          (16 KB)  -- zeroed via memsetAsync
//   [16384]              float ss[4096]          (16 KB)  -- zeroed via memsetAsync
//   [32768]              __bf16 XT[16][64][4096] ( 8 MiB)
//   [32768 + 8 MiB]      __bf16 A16[4096][4096]  (32 MiB)

// ---------------------------------------------------------------------------
// Kernel 1: flat scatter build. j-major: lane-consecutive loads AND stores.
// ---------------------------------------------------------------------------
__global__ __launch_bounds__(256) void build_kernel(
    const float* __restrict__ inc, float* __restrict__ out_inc,
    __bf16* __restrict__ A16, float* __restrict__ mxa, float* __restrict__ ssa)
{
    int t = threadIdx.x;
    int base = blockIdx.x << 12;                 // 4096 elems per block
    int rA = (int)((unsigned)base / NM1);        // block spans rows {rA, rA+1}
    float pm0 = 0.f, ps0 = 0.f, pm1 = 0.f, ps1 = 0.f;
    #pragma unroll
    for (int j = 0; j < 16; ++j) {
        int f = base + j * 256 + t;              // < 2^24, exact coverage
        int i = (int)((unsigned)f / NM1);
        int c = f - i * NM1;
        float x = inc[f];
        float w = x > 0.01f ? x : 0.f;
        int dst = f + i + (c >= i);              // i*4096 + c + (c>=i)
        out_inc[dst] = w;
        A16[dst] = (__bf16)w;
        if (i == rA) { pm0 = fmaxf(pm0, w); ps0 += w * w; }
        else         { pm1 = fmaxf(pm1, w); ps1 += w * w; }
    }
    #pragma unroll
    for (int off = 32; off; off >>= 1) {
        pm0 = fmaxf(pm0, __shfl_down(pm0, off));
        ps0 += __shfl_down(ps0, off);
        pm1 = fmaxf(pm1, __shfl_down(pm1, off));
        ps1 += __shfl_down(ps1, off);
    }
    __shared__ float sm0[4], sq0[4], sm1[4], sq1[4];
    int wid = t >> 6;
    if ((t & 63) == 0) { sm0[wid] = pm0; sq0[wid] = ps0; sm1[wid] = pm1; sq1[wid] = ps1; }
    __syncthreads();
    if (t == 0) {
        float m0v = fmaxf(fmaxf(sm0[0], sm0[1]), fmaxf(sm0[2], sm0[3]));
        float s0v = sq0[0] + sq0[1] + sq0[2] + sq0[3];
        float m1v = fmaxf(fmaxf(sm1[0], sm1[1]), fmaxf(sm1[2], sm1[3]));
        float s1v = sq1[0] + sq1[1] + sq1[2] + sq1[3];
        atomicMax((unsigned*)(mxa + rA), __float_as_uint(m0v));  // w >= 0
        atomicAdd(ssa + rA, s0v);
        int rB = rA + 1;
        if (rB < NN) {
            atomicMax((unsigned*)(mxa + rB), __float_as_uint(m1v));
            atomicAdd(ssa + rB, s1v);
        }
    }
}

// ---------------------------------------------------------------------------
// Kernel 2: XT[b][d][n] = (bf16)X[b][n][d]  (64x64 tiles via LDS) + diagonal
// ---------------------------------------------------------------------------
__global__ __launch_bounds__(256) void xt_kernel(
    const float* __restrict__ X, __bf16* __restrict__ XT,
    float* __restrict__ out_inc, __bf16* __restrict__ A16)
{
    __shared__ __bf16 tile[64 * 72];             // stride 72 elems = 144 B
    int t = threadIdx.x;
    int ntile = blockIdx.x, b = blockIdx.y;
    int n = t >> 2, q = t & 3;
    const float* src = X + ((size_t)b * NN + ntile * 64 + n) * DD + q * 16;
    #pragma unroll
    for (int v = 0; v < 4; ++v) {
        f32x4 u = *(const f32x4*)(src + v * 4);
        #pragma unroll
        for (int j = 0; j < 4; ++j) {
            int d = q * 16 + v * 4 + j;
            tile[d * 72 + n] = (__bf16)u[j];
        }
    }
    __syncthreads();
    int d = t >> 2;
    __bf16* dst = XT + ((size_t)b * DD + d) * NN + ntile * 64 + q * 16;
    *(bf16x8*)dst       = *(bf16x8*)&tile[d * 72 + q * 16];
    *(bf16x8*)(dst + 8) = *(bf16x8*)&tile[d * 72 + q * 16 + 8];
    if (b == 0 && t < 64) {                      // diagonal of W + I
        int r = ntile * 64 + t;
        out_inc[(size_t)r * NN + r] = 1.0f;
        A16[(size_t)r * NN + r] = (__bf16)1.0f;
    }
}

// ---------------------------------------------------------------------------
// Kernel 3: acc = A16 @ X[b] via MFMA (R1 structure + deeper pipeline).
//   block = 128 rows x 64 cols x 2 batches; 512 thr / 8 waves (2/SIMD);
//   wave = 32 rows x 64 cols of one batch.
//   4 x 32 KB LDS buffers, prefetch depth 3, steady vmcnt(8), ONE raw
//   s_barrier per k-step (stage(kt+3) issued AFTER compute(kt): buffer
//   (kt+3)&3 == (kt-1)&3 was last read before barrier#kt -> safe).
//   s_setprio(1) around MFMA cluster. Fused xp phase: dif = xp - acc.
// ---------------------------------------------------------------------------
__global__ __launch_bounds__(512, 2) void gemm_loss_kernel(
    const __bf16* __restrict__ A16, const __bf16* __restrict__ XT,
    const float* __restrict__ X, const float* __restrict__ rproj,
    const float* __restrict__ mxa, const float* __restrict__ ssa,
    float* __restrict__ loss)
{
    // buffer c at smem + c*16384:  A[128][64] then X[2][64][64] (flat [128][64])
    __shared__ __bf16 smem[4 * 16384];           // 128 KB

    const int t = threadIdx.x;
    const int wave = t >> 6, lane = t & 63;
    const int quad = lane >> 4, ln = lane & 15;
    const int sr = lane >> 3, so = lane & 7;     // staging row-in-group / octet
    const int bq = wave >> 2;                    // batch within pair (0/1)
    const int wr = (wave & 3) << 5;              // wave row offset: 0/32/64/96
    const int m0 = blockIdx.x * 128;
    const int b0 = blockIdx.y * 2;

    const __bf16* Abase = A16 + (size_t)m0 * NN;
    const __bf16* XTb   = XT + (size_t)b0 * DD * NN;   // 2 batches, flat 128 rows

    f32x4 acc[2][4];
    f32x4 zero = {0.f, 0.f, 0.f, 0.f};
    #pragma unroll
    for (int mt = 0; mt < 2; ++mt)
        #pragma unroll
        for (int ct = 0; ct < 4; ++ct) acc[mt][ct] = zero;

    // stage one 64-wide k-step into buffer `buf`: A 16 KB + X 16 KB,
    // 4 global_load_lds (16 B) per thread, XOR-octet pre-swizzled source.
    auto stage = [&](int buf, int kt) {
        __bf16* bA = smem + buf * 16384;
        __bf16* bX = bA + 8192;
        const int k0 = kt << 6;
        #pragma unroll
        for (int p = 0; p < 2; ++p) {
            const int r0 = (p << 6) + (wave << 3);   // wave-uniform 8-row group
            const int r  = r0 + sr;
            const int og = so ^ (r & 7);             // LDS[r][o] = G[r][o^(r&7)]
            __builtin_amdgcn_global_load_lds(
                (gas_void*)(Abase + (size_t)r * NN + k0 + (og << 3)),
                (las_void*)(bA + r0 * 64), 16, 0, 0);
            __builtin_amdgcn_global_load_lds(
                (gas_void*)(XTb + (size_t)r * NN + k0 + (og << 3)),
                (las_void*)(bX + r0 * 64), 16, 0, 0);
        }
    };

    auto compute = [&](int buf) {
        const __bf16* bA = smem + buf * 16384;
        const __bf16* bX = bA + 8192 + (bq << 12);   // this wave's batch [64][64]
        __builtin_amdgcn_s_setprio(1);
        #pragma unroll
        for (int kk = 0; kk < 64; kk += 32) {
            const int oc = (kk >> 3) + quad;
            bf16x8 af[2], bfr[4];
            #pragma unroll
            for (int mt = 0; mt < 2; ++mt) {
                const int r = wr + mt * 16 + ln;
                af[mt] = *(const bf16x8*)&bA[r * 64 + ((oc ^ (r & 7)) << 3)];
            }
            #pragma unroll
            for (int ct = 0; ct < 4; ++ct) {
                const int n = ct * 16 + ln;
                bfr[ct] = *(const bf16x8*)&bX[n * 64 + ((oc ^ (n & 7)) << 3)];
            }
            #pragma unroll
            for (int mt = 0; mt < 2; ++mt)
                #pragma unroll
                for (int ct = 0; ct < 4; ++ct)
                    acc[mt][ct] = __builtin_amdgcn_mfma_f32_16x16x32_bf16(
                        af[mt], bfr[ct], acc[mt][ct], 0, 0, 0);
        }
        __builtin_amdgcn_s_setprio(0);
    };

    const int NT = NN / 64;                      // 64 k-steps
    stage(0, 0);
    stage(1, 1);
    stage(2, 2);
    for (int kt = 0; kt < NT - 3; ++kt) {        // kt = 0..60
        asm volatile("s_waitcnt vmcnt(8)" ::: "memory");
        __builtin_amdgcn_s_barrier();
        __builtin_amdgcn_sched_barrier(0);
        compute(kt & 3);
        stage((kt + 3) & 3, kt + 3);
    }
    // kt = 61
    asm volatile("s_waitcnt vmcnt(8)" ::: "memory");
    __builtin_amdgcn_s_barrier();
    __builtin_amdgcn_sched_barrier(0);
    compute(1);
    // kt = 62
    asm volatile("s_waitcnt vmcnt(4)" ::: "memory");
    __builtin_amdgcn_s_barrier();
    __builtin_amdgcn_sched_barrier(0);
    compute(2);
    // kt = 63
    asm volatile("s_waitcnt vmcnt(0)" ::: "memory");
    __builtin_amdgcn_s_barrier();
    __builtin_amdgcn_sched_barrier(0);
    compute(3);

    __syncthreads();                             // all compute done before reuse

    // ---- phase 2 staging: XA[2][128][64] = bf16(X rows), R[64][64] = r+I ----
    {
        const int rr = t >> 2, q = t & 3;        // rr in [0,128)
        #pragma unroll
        for (int bb = 0; bb < 2; ++bb) {
            const float* xs = X + ((size_t)(b0 + bb) * NN + m0 + rr) * DD + q * 16;
            __bf16* XA = smem + bb * 8192;
            #pragma unroll
            for (int v = 0; v < 2; ++v) {
                f32x4 u0 = *(const f32x4*)(xs + v * 8);
                f32x4 u1 = *(const f32x4*)(xs + v * 8 + 4);
                bf16x8 w;
                #pragma unroll
                for (int j = 0; j < 4; ++j) { w[j] = (__bf16)u0[j]; w[j + 4] = (__bf16)u1[j]; }
                const int o = (q * 2 + v) ^ (rr & 7);
                *(bf16x8*)&XA[rr * 64 + o * 8] = w;
            }
        }
        if (t < 256) {
            const int rr2 = t >> 2, q2 = t & 3;  // rr2 in [0,64): rproj row e
            const float* rs = rproj + (size_t)rr2 * DD + q2 * 16;
            __bf16* R = smem + 16384;
            #pragma unroll
            for (int v = 0; v < 4; ++v) {
                f32x4 u = *(const f32x4*)(rs + v * 4);
                #pragma unroll
                for (int j = 0; j < 4; ++j) {
                    const int d = q2 * 16 + v * 4 + j;
                    float val = u[j] + (d == rr2 ? 1.0f : 0.0f);   // r + I
                    R[d * 64 + (((rr2 >> 3) ^ (d & 7)) << 3) + (rr2 & 7)] = (__bf16)val;
                }
            }
        }
    }
    __syncthreads();

    // ---- xp phase accumulates into -acc: dif = X@(r+I) - acc ----
    #pragma unroll
    for (int mt = 0; mt < 2; ++mt)
        #pragma unroll
        for (int ct = 0; ct < 4; ++ct) acc[mt][ct] = -acc[mt][ct];

    {
        const __bf16* XA = smem + bq * 8192;
        const __bf16* R  = smem + 16384;
        #pragma unroll
        for (int kk = 0; kk < DD; kk += 32) {
            const int oc = (kk >> 3) + quad;
            bf16x8 af[2], bfr[4];
            #pragma unroll
            for (int mt = 0; mt < 2; ++mt) {
                const int r = wr + mt * 16 + ln;
                af[mt] = *(const bf16x8*)&XA[r * 64 + ((oc ^ (r & 7)) << 3)];
            }
            #pragma unroll
            for (int ct = 0; ct < 4; ++ct) {
                const int n = ct * 16 + ln;
                bfr[ct] = *(const bf16x8*)&R[n * 64 + ((oc ^ (n & 7)) << 3)];
            }
            #pragma unroll
            for (int mt = 0; mt < 2; ++mt)
                #pragma unroll
                for (int ct = 0; ct < 4; ++ct)
                    acc[mt][ct] = __builtin_amdgcn_mfma_f32_16x16x32_bf16(
                        af[mt], bfr[ct], acc[mt][ct], 0, 0, 0);
        }
    }

    // ---- epilogue: C/D layout col=ln, row=quad*4+reg; wave owns full rows ----
    #pragma unroll
    for (int mt = 0; mt < 2; ++mt) {
        #pragma unroll
        for (int rg = 0; rg < 4; ++rg) {
            float s = 0.f;
            #pragma unroll
            for (int ct = 0; ct < 4; ++ct) {
                float d = acc[mt][ct][rg];
                s += d * d;
            }
            s += __shfl_xor(s, 1);
            s += __shfl_xor(s, 2);
            s += __shfl_xor(s, 4);
            s += __shfl_xor(s, 8);
            if (ln == 0) {
                int row = m0 + wr + mt * 16 + quad * 4 + rg;
                loss[(size_t)(b0 + bq) * NN + row] =
                    0.2f * sqrtf(s) + mxa[row] + 0.001f * sqrtf(ssa[row]);
            }
        }
    }
}

extern "C" void kernel_launch(void* const* d_in, const int* in_sizes, int n_in,
                              void* d_out, int out_size, void* d_ws, size_t ws_size,
                              hipStream_t stream) {
    const float* X   = (const float*)d_in[0];   // [B][N][D] f32
    const float* r   = (const float*)d_in[1];   // [D][D] f32
    const float* inc = (const float*)d_in[2];   // [N][N-1] f32
    float* out      = (float*)d_out;
    float* out_loss = out;                       // [B][N]
    float* out_inc  = out + (size_t)BB * NN;     // [N][N]

    char* ws = (char*)d_ws;
    float*  mxa = (float*)ws;                               // 16 KB
    float*  ssa = (float*)(ws + 16384);                     // 16 KB
    __bf16* XT  = (__bf16*)(ws + 32768);                    //  8 MiB
    __bf16* A16 = (__bf16*)(ws + 32768 + (size_t)8 * 1024 * 1024);  // 32 MiB

    hipMemsetAsync(mxa, 0, 32768, stream);      // zero mx/ss accumulators

    hipLaunchKernelGGL(build_kernel, dim3(NM1), dim3(256), 0, stream,
                       inc, out_inc, A16, mxa, ssa);
    hipLaunchKernelGGL(xt_kernel, dim3(NN / 64, BB), dim3(256), 0, stream,
                       X, XT, out_inc, A16);
    hipLaunchKernelGGL(gemm_loss_kernel, dim3(NN / 128, BB / 2), dim3(512), 0, stream,
                       A16, XT, X, r, mxa, ssa, out_loss);
}